// Round 15
// baseline (79.893 us; speedup 1.0000x reference)
//
#include <hip/hip_runtime.h>

#define S 512
#define Dm 512

typedef __bf16 bf16x8 __attribute__((ext_vector_type(8)));
typedef float f32x4 __attribute__((ext_vector_type(4)));

// ---------------- bf16 MFMA GEMM with inline fp32->bf16 conversion (r8) ----------------
template<bool A_BF16>
__global__ __launch_bounds__(256) void gemm_icvt(
    const void* __restrict__ Aptr,
    const float* __restrict__ W0, const float* __restrict__ W1, const float* __restrict__ W2,
    const float* __restrict__ b0, const float* __restrict__ b1, const float* __restrict__ b2,
    float* __restrict__ O0, float* __restrict__ O1, float* __restrict__ O2)
{
    int blk = blockIdx.x;
    int m = blk >> 8;
    int tile = blk & 255;
    const float* W = (m == 0) ? W0 : (m == 1) ? W1 : W2;
    const float* bias = (m == 0) ? b0 : (m == 1) ? b1 : b2;
    float* O = (m == 0) ? O0 : (m == 1) ? O1 : O2;
    int rt = tile >> 4, ct = tile & 15;

    int u = threadIdx.x;
    int w = u >> 6, lane = u & 63;
    int r = lane & 15, kg = lane >> 4;

    int row0 = (rt << 5) + ((w >> 1) << 4);
    int col0 = (ct << 5) + ((w & 1) << 4);

    const float* Bp = W + (kg << 3) * Dm + col0 + r;

    f32x4 acc = {0.f, 0.f, 0.f, 0.f};

    #pragma unroll 4
    for (int k0 = 0; k0 < Dm; k0 += 32) {
        bf16x8 a;
        if constexpr (A_BF16) {
            const __bf16* Ab = (const __bf16*)Aptr;
            a = *(const bf16x8*)(Ab + (row0 + r) * Dm + k0 + (kg << 3));
        } else {
            const float* Af = (const float*)Aptr;
            float4 a0 = *(const float4*)(Af + (row0 + r) * Dm + k0 + (kg << 3));
            float4 a1 = *(const float4*)(Af + (row0 + r) * Dm + k0 + (kg << 3) + 4);
            a[0] = (__bf16)a0.x; a[1] = (__bf16)a0.y; a[2] = (__bf16)a0.z; a[3] = (__bf16)a0.w;
            a[4] = (__bf16)a1.x; a[5] = (__bf16)a1.y; a[6] = (__bf16)a1.z; a[7] = (__bf16)a1.w;
        }
        bf16x8 b;
        #pragma unroll
        for (int t = 0; t < 8; ++t)
            b[t] = (__bf16)Bp[(k0 + t) * Dm];
        acc = __builtin_amdgcn_mfma_f32_16x16x32_bf16(a, b, acc, 0, 0, 0);
    }

    int orow = row0 + (kg << 2);
    float bb = bias[col0 + r];
    #pragma unroll
    for (int t = 0; t < 4; ++t)
        O[(orow + t) * Dm + col0 + r] = acc[t] + bb;
}

// ---------------- z-pass, outer-product register-tiled ----------------
// grid 512 = 8 heads * 8 i-tiles(64) * 8 j-tiles(64). 512 thr = 8 waves (2 wi x 4 wj).
// wave tile 32i x 16j; lane (li=lane&7, lj=lane>>3) owns 4i x 2j.
// Per 4-d step: 6 float4 loads -> 64 VALU ops (11:1 VALU:VMEM instrs).
__global__ __launch_bounds__(512) void zop_kernel(
    const float* __restrict__ Q, const float* __restrict__ K,
    const float* __restrict__ mask, const float* __restrict__ gamma,
    const float* __restrict__ alpha,
    float* __restrict__ zp, float* __restrict__ Zpart)
{
    int blk = blockIdx.x;
    int h  = blk >> 6;
    int it = (blk >> 3) & 7;
    int jt = blk & 7;
    int i0 = it << 6;
    int j0 = jt << 6;
    int c0 = h << 6;

    int u = threadIdx.x;
    int w = u >> 6, lane = u & 63;
    int wi = w >> 2, wj = w & 3;       // 2 x 4 waves
    int li = lane & 7, lj = lane >> 3; // 8 x 8 lanes

    int ib = i0 + (wi << 5) + (li << 2);   // rows ib..ib+3
    int jb = j0 + (wj << 4) + (lj << 1);   // cols jb, jb+1

    const float* qp = Q + ib * Dm + c0;
    const float* kp = K + jb * Dm + c0;

    __shared__ float zsl[64][4];

    float acc[4][2] = {};

    #pragma unroll 4
    for (int d4 = 0; d4 < 64; d4 += 4) {
        float4 q0 = *(const float4*)(qp + 0 * Dm + d4);
        float4 q1 = *(const float4*)(qp + 1 * Dm + d4);
        float4 q2 = *(const float4*)(qp + 2 * Dm + d4);
        float4 q3 = *(const float4*)(qp + 3 * Dm + d4);
        float4 k0 = *(const float4*)(kp + 0 * Dm + d4);
        float4 k1 = *(const float4*)(kp + 1 * Dm + d4);

        acc[0][0] += fabsf(q0.x - k0.x) + fabsf(q0.y - k0.y) + fabsf(q0.z - k0.z) + fabsf(q0.w - k0.w);
        acc[0][1] += fabsf(q0.x - k1.x) + fabsf(q0.y - k1.y) + fabsf(q0.z - k1.z) + fabsf(q0.w - k1.w);
        acc[1][0] += fabsf(q1.x - k0.x) + fabsf(q1.y - k0.y) + fabsf(q1.z - k0.z) + fabsf(q1.w - k0.w);
        acc[1][1] += fabsf(q1.x - k1.x) + fabsf(q1.y - k1.y) + fabsf(q1.z - k1.z) + fabsf(q1.w - k1.w);
        acc[2][0] += fabsf(q2.x - k0.x) + fabsf(q2.y - k0.y) + fabsf(q2.z - k0.z) + fabsf(q2.w - k0.w);
        acc[2][1] += fabsf(q2.x - k1.x) + fabsf(q2.y - k1.y) + fabsf(q2.z - k1.z) + fabsf(q2.w - k1.w);
        acc[3][0] += fabsf(q3.x - k0.x) + fabsf(q3.y - k0.y) + fabsf(q3.z - k0.z) + fabsf(q3.w - k0.w);
        acc[3][1] += fabsf(q3.x - k1.x) + fabsf(q3.y - k1.y) + fabsf(q3.z - k1.z) + fabsf(q3.w - k1.w);
    }

    float sc = 1.0f / (gamma[0] * 8.0f);
    float al = alpha[0];
    float m0 = (1.0f - mask[jb + 0]) * 1e6f;
    float m1 = (1.0f - mask[jb + 1]) * 1e6f;

    float zs[4];
    #pragma unroll
    for (int r = 0; r < 4; ++r) {
        float z0 = fmaxf(acc[r][0] * sc - al, 0.0f) + m0;
        float z1 = fmaxf(acc[r][1] * sc - al, 0.0f) + m1;
        // contiguous float2 store: 8 lj lanes cover 16 consecutive j
        float2 st = make_float2(z0, z1);
        *(float2*)(zp + ((h << 9) + ib + r) * S + jb) = st;
        zs[r] = z0 + z1;
    }

    // reduce Zsum over lj (lanes sharing the same rows): xor 8,16,32
    #pragma unroll
    for (int r = 0; r < 4; ++r) {
        float v = zs[r];
        v += __shfl_xor(v, 8, 64);
        v += __shfl_xor(v, 16, 64);
        v += __shfl_xor(v, 32, 64);
        zs[r] = v;
    }
    if (lj == 0) {
        #pragma unroll
        for (int r = 0; r < 4; ++r)
            zsl[(wi << 5) + (li << 2) + r][wj] = zs[r];
    }
    __syncthreads();

    if (u < 64) {
        float z4 = zsl[u][0] + zsl[u][1] + zsl[u][2] + zsl[u][3];
        Zpart[((h << 9) + i0 + u) * 8 + jt] = z4;
    }
}

// ---------------- ctx (r8): sum_j max(v,z') - Zsum; z' scalar-uniform, V per-lane ----------------
__global__ __launch_bounds__(512) void ctx_kernel(
    const float* __restrict__ V, const float* __restrict__ zp,
    const float* __restrict__ Zpart, __bf16* __restrict__ ctxb)
{
    int blk = blockIdx.x;
    int h = blk >> 6;
    int it = blk & 63;
    int i0 = it << 3;
    int c0 = h << 6;
    int u = threadIdx.x;
    int w = u >> 6, lane = u & 63;

    __shared__ float part[8][8][64];

    int wu = __builtin_amdgcn_readfirstlane(w);
    float acc[8][4] = {};

    #pragma unroll
    for (int cch = 0; cch < 4; ++cch) {
        int jg = (cch << 7) + (wu << 4);
        float vv[16];
        #pragma unroll
        for (int t = 0; t < 16; ++t)
            vv[t] = V[(jg + t) * Dm + c0 + lane];

        const float* zbase = zp + ((h << 9) + i0) * S + jg;
        #pragma unroll
        for (int ii = 0; ii < 8; ++ii) {
            const float* zrow = zbase + ii * S;
            #pragma unroll
            for (int q4 = 0; q4 < 4; ++q4) {
                float4 z4 = *(const float4*)(zrow + (q4 << 2));
                acc[ii][0] += fmaxf(vv[(q4 << 2) + 0], z4.x);
                acc[ii][1] += fmaxf(vv[(q4 << 2) + 1], z4.y);
                acc[ii][2] += fmaxf(vv[(q4 << 2) + 2], z4.z);
                acc[ii][3] += fmaxf(vv[(q4 << 2) + 3], z4.w);
            }
        }
    }

    #pragma unroll
    for (int ii = 0; ii < 8; ++ii)
        part[w][ii][lane] = (acc[ii][0] + acc[ii][1]) + (acc[ii][2] + acc[ii][3]);
    __syncthreads();
    {
        int ii = u >> 6;
        float s = 0.f;
        #pragma unroll
        for (int ww = 0; ww < 8; ++ww) s += part[ww][ii][lane];
        float zsum = 0.f;
        const float* zpr = Zpart + ((h << 9) + (i0 + ii)) * 8;
        #pragma unroll
        for (int p = 0; p < 8; ++p) zsum += zpr[p];
        ctxb[(i0 + ii) * Dm + c0 + lane] = (__bf16)(s - zsum);
    }
}

extern "C" void kernel_launch(void* const* d_in, const int* in_sizes, int n_in,
                              void* d_out, int out_size, void* d_ws, size_t ws_size,
                              hipStream_t stream) {
    const float* hs    = (const float*)d_in[0];
    const float* mask  = (const float*)d_in[1];
    const float* Wq    = (const float*)d_in[2];
    const float* bq    = (const float*)d_in[3];
    const float* Wk    = (const float*)d_in[4];
    const float* bk    = (const float*)d_in[5];
    const float* Wv    = (const float*)d_in[6];
    const float* bv    = (const float*)d_in[7];
    const float* Wo    = (const float*)d_in[8];
    const float* bo    = (const float*)d_in[9];
    const float* gamma = (const float*)d_in[10];
    const float* alpha = (const float*)d_in[11];
    float* out = (float*)d_out;

    char* base = (char*)d_ws;
    float*  zp    = (float*)(base);                               // 8 MB
    float*  Zpart = (float*)(base + (8u << 20));                  // 128 KB
    float*  Qb    = (float*)(base + (8u << 20) + (128u << 10));   // 1 MB
    float*  Kb    = Qb + S * Dm;                                  // 1 MB
    float*  Vb    = Kb + S * Dm;                                  // 1 MB
    __bf16* Cbf   = (__bf16*)(Vb + S * Dm);                       // 0.5 MB

    hipLaunchKernelGGL((gemm_icvt<false>), dim3(768), dim3(256), 0, stream,
                       (const void*)hs, Wq, Wk, Wv, bq, bk, bv, Qb, Kb, Vb);
    hipLaunchKernelGGL(zop_kernel, dim3(512), dim3(512), 0, stream,
                       Qb, Kb, mask, gamma, alpha, zp, Zpart);
    hipLaunchKernelGGL(ctx_kernel, dim3(512), dim3(512), 0, stream,
                       Vb, zp, Zpart, Cbf);
    hipLaunchKernelGGL((gemm_icvt<true>), dim3(256), dim3(256), 0, stream,
                       (const void*)Cbf, Wo, Wo, Wo, bo, bo, bo, out, out, out);
}

// Round 16
// 58.741 us; speedup vs baseline: 1.3601x; 1.3601x over previous
//
#include <hip/hip_runtime.h>

#define S 512
#define Dm 512

typedef __bf16 bf16x8 __attribute__((ext_vector_type(8)));
typedef float f32x4 __attribute__((ext_vector_type(4)));

// ---------------- bf16 MFMA GEMM with inline fp32->bf16 conversion (r8) ----------------
template<bool A_BF16>
__global__ __launch_bounds__(256) void gemm_icvt(
    const void* __restrict__ Aptr,
    const float* __restrict__ W0, const float* __restrict__ W1, const float* __restrict__ W2,
    const float* __restrict__ b0, const float* __restrict__ b1, const float* __restrict__ b2,
    float* __restrict__ O0, float* __restrict__ O1, float* __restrict__ O2)
{
    int blk = blockIdx.x;
    int m = blk >> 8;
    int tile = blk & 255;
    const float* W = (m == 0) ? W0 : (m == 1) ? W1 : W2;
    const float* bias = (m == 0) ? b0 : (m == 1) ? b1 : b2;
    float* O = (m == 0) ? O0 : (m == 1) ? O1 : O2;
    int rt = tile >> 4, ct = tile & 15;

    int u = threadIdx.x;
    int w = u >> 6, lane = u & 63;
    int r = lane & 15, kg = lane >> 4;

    int row0 = (rt << 5) + ((w >> 1) << 4);
    int col0 = (ct << 5) + ((w & 1) << 4);

    const float* Bp = W + (kg << 3) * Dm + col0 + r;

    f32x4 acc = {0.f, 0.f, 0.f, 0.f};

    #pragma unroll 4
    for (int k0 = 0; k0 < Dm; k0 += 32) {
        bf16x8 a;
        if constexpr (A_BF16) {
            const __bf16* Ab = (const __bf16*)Aptr;
            a = *(const bf16x8*)(Ab + (row0 + r) * Dm + k0 + (kg << 3));
        } else {
            const float* Af = (const float*)Aptr;
            float4 a0 = *(const float4*)(Af + (row0 + r) * Dm + k0 + (kg << 3));
            float4 a1 = *(const float4*)(Af + (row0 + r) * Dm + k0 + (kg << 3) + 4);
            a[0] = (__bf16)a0.x; a[1] = (__bf16)a0.y; a[2] = (__bf16)a0.z; a[3] = (__bf16)a0.w;
            a[4] = (__bf16)a1.x; a[5] = (__bf16)a1.y; a[6] = (__bf16)a1.z; a[7] = (__bf16)a1.w;
        }
        bf16x8 b;
        #pragma unroll
        for (int t = 0; t < 8; ++t)
            b[t] = (__bf16)Bp[(k0 + t) * Dm];
        acc = __builtin_amdgcn_mfma_f32_16x16x32_bf16(a, b, acc, 0, 0, 0);
    }

    int orow = row0 + (kg << 2);
    float bb = bias[col0 + r];
    #pragma unroll
    for (int t = 0; t < 4; ++t)
        O[(orow + t) * Dm + col0 + r] = acc[t] + bb;
}

// ---------------- z-pass: Q staged via LDS (coalesced), qreg from LDS; K scalar ----------------
// grid 512 = 8 heads * 8 i-tiles(64) * 8 j-tiles(64). 512 thr = 8 waves; wave w: 8 j's.
__global__ __launch_bounds__(512) void zfast_kernel(
    const float* __restrict__ Q, const float* __restrict__ K,
    const float* __restrict__ mask, const float* __restrict__ gamma,
    const float* __restrict__ alpha,
    float* __restrict__ zp, float* __restrict__ Zpart)
{
    int blk = blockIdx.x;
    int h  = blk >> 6;
    int it = (blk >> 3) & 7;
    int jt = blk & 7;
    int i0 = it << 6;
    int j0 = jt << 6;
    int c0 = h << 6;

    int u = threadIdx.x;
    int w = u >> 6, lane = u & 63;

    // shared memory: Qs (phase 1) aliases {zsT, partial} (phase 2)
    __shared__ char smem_raw[18688];
    float (*Qs)[68]     = (float (*)[68])smem_raw;                 // 64x68x4 = 17408 B
    float (*zsT)[65]    = (float (*)[65])smem_raw;                 // 64x65x4 = 16640 B
    float (*partial)[64] = (float (*)[64])(smem_raw + 16640);      // 8x64x4 = 2048 B

    // ---- phase 1: stage Q tile coalesced, then per-lane row from LDS ----
    {
        int row = u >> 3;              // 0..63
        int cg = (u & 7) << 3;         // 0..56
        float4 a0 = *(const float4*)(Q + (i0 + row) * Dm + c0 + cg);
        float4 a1 = *(const float4*)(Q + (i0 + row) * Dm + c0 + cg + 4);
        *(float4*)&Qs[row][cg] = a0;
        *(float4*)&Qs[row][cg + 4] = a1;
    }
    __syncthreads();

    float qreg[64];
    #pragma unroll
    for (int t = 0; t < 16; ++t) {
        float4 qv = *(const float4*)&Qs[lane][t << 2];   // b128, balanced banks (pad 68)
        qreg[4 * t + 0] = qv.x; qreg[4 * t + 1] = qv.y;
        qreg[4 * t + 2] = qv.z; qreg[4 * t + 3] = qv.w;
    }
    __syncthreads();                   // Qs dead; zsT/partial may now be written

    float sc = 1.0f / (gamma[0] * 8.0f);
    float al = alpha[0];

    int jb = __builtin_amdgcn_readfirstlane(w << 3);

    float zsum = 0.f;
    #pragma unroll 2
    for (int jj = 0; jj < 8; ++jj) {
        const float* kr = K + (j0 + jb + jj) * Dm + c0;   // uniform pointer -> scalar path
        float a0 = 0.f, a1 = 0.f, a2 = 0.f, a3 = 0.f;
        #pragma unroll
        for (int t = 0; t < 16; ++t) {
            float4 kb = *(const float4*)(kr + (t << 2));
            a0 += fabsf(qreg[4 * t + 0] - kb.x);
            a1 += fabsf(qreg[4 * t + 1] - kb.y);
            a2 += fabsf(qreg[4 * t + 2] - kb.z);
            a3 += fabsf(qreg[4 * t + 3] - kb.w);
        }
        float madd = (1.0f - mask[j0 + jb + jj]) * 1e6f;
        float zpv = fmaxf((a0 + a1 + a2 + a3) * sc - al, 0.0f) + madd;
        zsT[jb + jj][lane] = zpv;
        zsum += zpv;
    }
    partial[w][lane] = zsum;
    __syncthreads();

    if (u < 64) {
        float zs8 = 0.f;
        #pragma unroll
        for (int p = 0; p < 8; ++p) zs8 += partial[p][u];
        Zpart[((h << 9) + i0 + u) * 8 + jt] = zs8;
    }

    {
        int il = u >> 3;
        int jg = (u & 7) << 3;
        float* orow = zp + ((h << 9) + i0 + il) * S + j0 + jg;
        #pragma unroll
        for (int q4 = 0; q4 < 2; ++q4) {
            float4 o;
            o.x = zsT[jg + (q4 << 2) + 0][il];
            o.y = zsT[jg + (q4 << 2) + 1][il];
            o.z = zsT[jg + (q4 << 2) + 2][il];
            o.w = zsT[jg + (q4 << 2) + 3][il];
            *(float4*)(orow + (q4 << 2)) = o;
        }
    }
}

// ---------------- ctx (r8): sum_j max(v,z') - Zsum; z' scalar-uniform, V per-lane ----------------
__global__ __launch_bounds__(512) void ctx_kernel(
    const float* __restrict__ V, const float* __restrict__ zp,
    const float* __restrict__ Zpart, __bf16* __restrict__ ctxb)
{
    int blk = blockIdx.x;
    int h = blk >> 6;
    int it = blk & 63;
    int i0 = it << 3;
    int c0 = h << 6;
    int u = threadIdx.x;
    int w = u >> 6, lane = u & 63;

    __shared__ float part[8][8][64];

    int wu = __builtin_amdgcn_readfirstlane(w);
    float acc[8][4] = {};

    #pragma unroll
    for (int cch = 0; cch < 4; ++cch) {
        int jg = (cch << 7) + (wu << 4);
        float vv[16];
        #pragma unroll
        for (int t = 0; t < 16; ++t)
            vv[t] = V[(jg + t) * Dm + c0 + lane];

        const float* zbase = zp + ((h << 9) + i0) * S + jg;
        #pragma unroll
        for (int ii = 0; ii < 8; ++ii) {
            const float* zrow = zbase + ii * S;
            #pragma unroll
            for (int q4 = 0; q4 < 4; ++q4) {
                float4 z4 = *(const float4*)(zrow + (q4 << 2));
                acc[ii][0] += fmaxf(vv[(q4 << 2) + 0], z4.x);
                acc[ii][1] += fmaxf(vv[(q4 << 2) + 1], z4.y);
                acc[ii][2] += fmaxf(vv[(q4 << 2) + 2], z4.z);
                acc[ii][3] += fmaxf(vv[(q4 << 2) + 3], z4.w);
            }
        }
    }

    #pragma unroll
    for (int ii = 0; ii < 8; ++ii)
        part[w][ii][lane] = (acc[ii][0] + acc[ii][1]) + (acc[ii][2] + acc[ii][3]);
    __syncthreads();
    {
        int ii = u >> 6;
        float s = 0.f;
        #pragma unroll
        for (int ww = 0; ww < 8; ++ww) s += part[ww][ii][lane];
        float zsum = 0.f;
        const float* zpr = Zpart + ((h << 9) + (i0 + ii)) * 8;
        #pragma unroll
        for (int p = 0; p < 8; ++p) zsum += zpr[p];
        ctxb[(i0 + ii) * Dm + c0 + lane] = (__bf16)(s - zsum);
    }
}

extern "C" void kernel_launch(void* const* d_in, const int* in_sizes, int n_in,
                              void* d_out, int out_size, void* d_ws, size_t ws_size,
                              hipStream_t stream) {
    const float* hs    = (const float*)d_in[0];
    const float* mask  = (const float*)d_in[1];
    const float* Wq    = (const float*)d_in[2];
    const float* bq    = (const float*)d_in[3];
    const float* Wk    = (const float*)d_in[4];
    const float* bk    = (const float*)d_in[5];
    const float* Wv    = (const float*)d_in[6];
    const float* bv    = (const float*)d_in[7];
    const float* Wo    = (const float*)d_in[8];
    const float* bo    = (const float*)d_in[9];
    const float* gamma = (const float*)d_in[10];
    const float* alpha = (const float*)d_in[11];
    float* out = (float*)d_out;

    char* base = (char*)d_ws;
    float*  zp    = (float*)(base);                               // 8 MB
    float*  Zpart = (float*)(base + (8u << 20));                  // 128 KB
    float*  Qb    = (float*)(base + (8u << 20) + (128u << 10));   // 1 MB
    float*  Kb    = Qb + S * Dm;                                  // 1 MB
    float*  Vb    = Kb + S * Dm;                                  // 1 MB
    __bf16* Cbf   = (__bf16*)(Vb + S * Dm);                       // 0.5 MB

    hipLaunchKernelGGL((gemm_icvt<false>), dim3(768), dim3(256), 0, stream,
                       (const void*)hs, Wq, Wk, Wv, bq, bk, bv, Qb, Kb, Vb);
    hipLaunchKernelGGL(zfast_kernel, dim3(512), dim3(512), 0, stream,
                       Qb, Kb, mask, gamma, alpha, zp, Zpart);
    hipLaunchKernelGGL(ctx_kernel, dim3(512), dim3(512), 0, stream,
                       Vb, zp, Zpart, Cbf);
    hipLaunchKernelGGL((gemm_icvt<true>), dim3(256), dim3(256), 0, stream,
                       (const void*)Cbf, Wo, Wo, Wo, bo, bo, bo, out, out, out);
}